// Round 9
// baseline (583.342 us; speedup 1.0000x reference)
//
#include <hip/hip_runtime.h>
#include <hip/hip_bf16.h>
#include <math.h>

#define H 128
#define FEAT 9

typedef unsigned int uint;
typedef __attribute__((ext_vector_type(8))) short short8;   // 8 bf16 = 4 VGPR
typedef __attribute__((ext_vector_type(4))) float f32x4;

// round-to-nearest-even f32 -> bf16 (finite inputs)
__device__ inline uint f2bf(float f) {
  uint u = __float_as_uint(f);
  return (u + 0x7FFF + ((u >> 16) & 1)) >> 16;
}
__device__ inline uint pk_bf16(float a, float b) {
  return f2bf(a) | (f2bf(b) << 16);
}
#define BLO(u) __uint_as_float((u) << 16)
#define BHI(u) __uint_as_float((u) & 0xFFFF0000u)

// ---------------- Atom encoder: h[v] = bf16x2(sum_f emb[f, x[v,f], :]) -------
__global__ __launch_bounds__(256) void k_atom(const int* __restrict__ x,
    const float* __restrict__ emb, uint* __restrict__ h,
    int N, int Npad, int maxv) {
  int wid = (blockIdx.x * blockDim.x + threadIdx.x) >> 6;
  int lane = threadIdx.x & 63;
  if (wid >= Npad) return;
  float a0 = 0.f, a1 = 0.f;
  if (wid < N) {
    const int* xr = x + (size_t)wid * FEAT;
#pragma unroll
    for (int f = 0; f < FEAT; ++f) {
      int id = xr[f];
      float2 e2 = *(const float2*)(emb + ((size_t)f * maxv + id) * H + 2 * lane);
      a0 += e2.x; a1 += e2.y;
    }
  }
  h[(size_t)wid * 64 + lane] = pk_bf16(a0, a1);
}

// ---------------- degree count (by dst) ----------------
__global__ __launch_bounds__(256) void k_count(const int* __restrict__ dst,
    int* __restrict__ counts, int E) {
  int i = blockIdx.x * blockDim.x + threadIdx.x;
  if (i < E) atomicAdd(&counts[dst[i]], 1);
}

// dinv + padded counts: degree+1 (self edge) padded to multiple of 8
__global__ __launch_bounds__(256) void k_dinv(const int* __restrict__ counts,
    float* __restrict__ dinv, int* __restrict__ pcnt, int N) {
  int i = blockIdx.x * blockDim.x + threadIdx.x;
  if (i < N) {
    int c = counts[i];
    dinv[i] = rsqrtf((float)(c + 1));
    pcnt[i] = (c + 8) & ~7;          // >= c+1, multiple of 8, min 8
  }
}

// ---------------- hierarchical scan (over padded counts) ----------------
__global__ __launch_bounds__(256) void k_scan1(const int* __restrict__ counts,
    int* __restrict__ incl, int* __restrict__ bsum, int n) {
  __shared__ int ws[4];
  int t = threadIdx.x;
  int i = blockIdx.x * 256 + t;
  int lane = t & 63, w = t >> 6;
  int v = (i < n) ? counts[i] : 0;
  int s = v;
#pragma unroll
  for (int off = 1; off < 64; off <<= 1) {
    int u = __shfl_up(s, off, 64);
    if (lane >= off) s += u;
  }
  if (lane == 63) ws[w] = s;
  __syncthreads();
  if (t == 0) {
    int acc = 0;
#pragma unroll
    for (int j = 0; j < 4; ++j) { int tmp = ws[j]; ws[j] = acc; acc += tmp; }
  }
  __syncthreads();
  s += ws[w];
  if (i < n) incl[i] = s;
  if (t == 255) bsum[blockIdx.x] = s;
}

__global__ __launch_bounds__(256) void k_scan2(int* __restrict__ bsum, int nb) {
  __shared__ int ws[4];
  int t = threadIdx.x, lane = t & 63, w = t >> 6;
  int v = (t < nb) ? bsum[t] : 0;
  int s = v;
#pragma unroll
  for (int off = 1; off < 64; off <<= 1) {
    int u = __shfl_up(s, off, 64);
    if (lane >= off) s += u;
  }
  if (lane == 63) ws[w] = s;
  __syncthreads();
  if (t == 0) {
    int acc = 0;
#pragma unroll
    for (int j = 0; j < 4; ++j) { int tmp = ws[j]; ws[j] = acc; acc += tmp; }
  }
  __syncthreads();
  s += ws[w];
  if (t < nb) bsum[t] = s - v;   // exclusive
}

__global__ __launch_bounds__(256) void k_scan3(const int* __restrict__ incl,
    const int* __restrict__ boff, int* __restrict__ row_ptr, int n) {
  int i = blockIdx.x * 256 + threadIdx.x;
  if (i < n) row_ptr[i + 1] = incl[i] + boff[i >> 8];
  if (i == 0) row_ptr[0] = 0;
}

// ---------------- CSR fill (into padded layout) ----------------
__global__ __launch_bounds__(256) void k_fill(const int* __restrict__ src,
    const int* __restrict__ dst, const int* __restrict__ row_ptr,
    int* __restrict__ cursor, int* __restrict__ col, int E) {
  int i = blockIdx.x * blockDim.x + threadIdx.x;
  if (i < E) {
    int d = dst[i];
    int pos = atomicAdd(&cursor[d], 1);
    col[row_ptr[d] + pos] = src[i];
  }
}

// ---- pad fill: col[rp[v]+deg] = v (self edge), rest sentinel N (zero row) ---
__global__ __launch_bounds__(256) void k_pad(const int* __restrict__ counts,
    const int* __restrict__ rp, int* __restrict__ col, int N) {
  int v = blockIdx.x * 256 + threadIdx.x;
  if (v >= N) return;
  int s = rp[v] + counts[v];
  int e = rp[v + 1];
  col[s] = v;                               // self-loop as a real edge
  for (int i = s + 1; i < e; ++i) col[i] = N;
}

// ---------------- graph boundaries ----------------
__global__ __launch_bounds__(256) void k_bound(const int* __restrict__ batch,
    int* __restrict__ gstart, int N, int G) {
  int i = blockIdx.x * 256 + threadIdx.x;
  if (i > N) return;
  int lo = (i == 0) ? 0 : batch[i - 1] + 1;
  int hi = (i == N) ? G : batch[i];
  for (int g = lo; g <= hi; ++g) gstart[g] = i;
}

// ---------------- W transpose + bf16: wt[l][n][k] packed pairs ----------------
__global__ __launch_bounds__(256) void k_wt(const float* __restrict__ W,
    uint* __restrict__ wt, int total) {   // total = L*128*64
  int idx = blockIdx.x * 256 + threadIdx.x;
  if (idx >= total) return;
  int l = idx >> 13;
  int rem = idx & 8191;
  int n = rem >> 6;
  int k2 = rem & 63;
  const float* w = W + (size_t)l * H * H;
  float x0 = w[(size_t)(2 * k2) * H + n];
  float x1 = w[(size_t)(2 * k2 + 1) * H + n];
  wt[idx] = pk_bf16(x0, x1);
}

// ---------------- MFMA GEMM: ms = bf16(dinv * (A' @ W)) ----------------
// FUSED: A' = relu(sc*a+bb)+hold (BN fold computed in-block), written to Hnew.
// All node tensors packed bf16x2. 128x128 tile, 4 waves, XOR-swizzled LDS.
template <int FUSED>
__global__ __launch_bounds__(256) void k_gemm_mfma(
    const uint* __restrict__ Ap, const uint* __restrict__ Hp,
    uint* __restrict__ Hnew,
    const float* __restrict__ bn_sum, const float* __restrict__ bn_sq,
    const float* __restrict__ gamma, const float* __restrict__ beta,
    float invN,
    const uint* __restrict__ wt, uint* __restrict__ ms,
    const float* __restrict__ dinv, int N) {
  __shared__ uint4 smem4[4096];          // 64 KB: sA [0,32K), sB [32K,64K)
  __shared__ float scbb[256];
  char* smemc = (char*)smem4;
  int t = threadIdx.x;
  int row0 = blockIdx.x * 128;

  if (FUSED) {
    if (t < 128) {
      float mean = bn_sum[t] * invN;
      float var = bn_sq[t] * invN - mean * mean;
      float s = gamma[t] * rsqrtf(var + 1e-5f);
      scbb[t] = s;
      scbb[128 + t] = beta[t] - mean * s;
    }
    __syncthreads();
  }

  // ---- stage A (packed bf16 source), swizzled ----
#pragma unroll
  for (int it = 0; it < 8; ++it) {
    int i = t + it * 256;                 // uint4 slots over [128][16]
    int r = i >> 4;
    int c16 = i & 15;
    uint4 w4;
    if (FUSED) {
      uint4 av = *(const uint4*)(Ap + (size_t)(row0 + r) * 64 + c16 * 4);
      uint4 hv = *(const uint4*)(Hp + (size_t)(row0 + r) * 64 + c16 * 4);
      int c0 = c16 * 8;
      float4 s0 = *(const float4*)(scbb + c0);
      float4 s1 = *(const float4*)(scbb + c0 + 4);
      float4 b0 = *(const float4*)(scbb + 128 + c0);
      float4 b1 = *(const float4*)(scbb + 128 + c0 + 4);
      float n0 = fmaxf(s0.x * BLO(av.x) + b0.x, 0.f) + BLO(hv.x);
      float n1 = fmaxf(s0.y * BHI(av.x) + b0.y, 0.f) + BHI(hv.x);
      float n2 = fmaxf(s0.z * BLO(av.y) + b0.z, 0.f) + BLO(hv.y);
      float n3 = fmaxf(s0.w * BHI(av.y) + b0.w, 0.f) + BHI(hv.y);
      float n4 = fmaxf(s1.x * BLO(av.z) + b1.x, 0.f) + BLO(hv.z);
      float n5 = fmaxf(s1.y * BHI(av.z) + b1.y, 0.f) + BHI(hv.z);
      float n6 = fmaxf(s1.z * BLO(av.w) + b1.z, 0.f) + BLO(hv.w);
      float n7 = fmaxf(s1.w * BHI(av.w) + b1.w, 0.f) + BHI(hv.w);
      w4.x = pk_bf16(n0, n1); w4.y = pk_bf16(n2, n3);
      w4.z = pk_bf16(n4, n5); w4.w = pk_bf16(n6, n7);
      *(uint4*)(Hnew + (size_t)(row0 + r) * 64 + c16 * 4) = w4;
    } else {
      w4 = *(const uint4*)(Ap + (size_t)(row0 + r) * 64 + c16 * 4);
    }
    int byte = r * 256 + ((c16 * 16) ^ ((r & 7) << 4));
    *(uint4*)(smemc + byte) = w4;
  }
  // ---- stage B: wt bf16 [n][k], swizzled ----
#pragma unroll
  for (int it = 0; it < 8; ++it) {
    int i = t + it * 256;                 // uint4 slots over [128][16]
    int n = i >> 4;
    int k16 = i & 15;
    int byte = 32768 + n * 256 + ((k16 * 16) ^ ((n & 7) << 4));
    *(uint4*)(smemc + byte) = ((const uint4*)wt)[i];
  }
  __syncthreads();

  int wid = t >> 6, l = t & 63;
  int wm = wid >> 1, wn = wid & 1;
  int lr = l & 15, lg = l >> 4;           // frag row/col, k-group

  f32x4 acc[4][4];
#pragma unroll
  for (int mt = 0; mt < 4; ++mt)
#pragma unroll
    for (int nt = 0; nt < 4; ++nt) acc[mt][nt] = (f32x4)0.f;

#pragma unroll
  for (int kk = 0; kk < 4; ++kk) {
    int kbyte = kk * 64 + lg * 16;
    short8 af[4], bf[4];
#pragma unroll
    for (int mt = 0; mt < 4; ++mt) {
      int r = wm * 64 + mt * 16 + lr;
      af[mt] = *(const short8*)(smemc + r * 256 + (kbyte ^ ((r & 7) << 4)));
    }
#pragma unroll
    for (int nt = 0; nt < 4; ++nt) {
      int n = wn * 64 + nt * 16 + lr;
      bf[nt] = *(const short8*)(smemc + 32768 + n * 256 + (kbyte ^ ((n & 7) << 4)));
    }
#pragma unroll
    for (int mt = 0; mt < 4; ++mt)
#pragma unroll
      for (int nt = 0; nt < 4; ++nt)
        acc[mt][nt] = __builtin_amdgcn_mfma_f32_16x16x32_bf16(
            af[mt], bf[nt], acc[mt][nt], 0, 0, 0);
  }
  __syncthreads();   // all LDS reads done; sA space becomes sC

  // ---- epilogue: scale by dinv, bf16, bounce through LDS, coalesced out ----
  float dr[4][4];
#pragma unroll
  for (int mt = 0; mt < 4; ++mt)
#pragma unroll
    for (int j = 0; j < 4; ++j) {
      int grow = row0 + wm * 64 + mt * 16 + lg * 4 + j;
      dr[mt][j] = (grow < N) ? dinv[grow] : 0.f;
    }
#pragma unroll
  for (int mt = 0; mt < 4; ++mt)
#pragma unroll
    for (int nt = 0; nt < 4; ++nt)
#pragma unroll
      for (int j = 0; j < 4; ++j) {
        int lrow = wm * 64 + mt * 16 + lg * 4 + j;
        int lcol = wn * 64 + nt * 16 + lr;
        float val = acc[mt][nt][j] * dr[mt][j];
        *(short*)(smemc + lrow * 256 + lcol * 2) = (short)f2bf(val);
      }
  __syncthreads();
#pragma unroll
  for (int it = 0; it < 8; ++it) {
    int i = t + it * 256;                 // uint4 slots over [128][16]
    int r = i >> 4;
    int c16 = i & 15;
    uint4 v = *(const uint4*)(smemc + r * 256 + c16 * 16);
    ((uint4*)ms)[(size_t)(row0 + r) * 16 + c16] = v;
  }
}

// ------------- aggregate v6: R7 gather core, 4 nodes/wave (2x TLP) -----------
// 1 dword/lane per edge = one coalesced 256B row per instruction. Self-loop is
// a real padded edge. col in 16-wide chunks 2 ahead (mod-3), 3 gather slots.
__global__ __launch_bounds__(256) void k_agg(const uint* __restrict__ ms,
    const int* __restrict__ rp, const int* __restrict__ col,
    const float* __restrict__ dinv, const float* __restrict__ bias,
    uint* __restrict__ a, float* __restrict__ bn_sum, float* __restrict__ bn_sq,
    int N) {
  __shared__ float s_sum[128], s_sq[128];
  for (int i = threadIdx.x; i < 128; i += 256) { s_sum[i] = 0.f; s_sq[i] = 0.f; }
  __syncthreads();
  int lane = threadIdx.x & 63;
  int wi = (blockIdx.x * 256 + threadIdx.x) >> 6;
  float b0 = bias[2 * lane], b1 = bias[2 * lane + 1];
  float lsum0 = 0.f, lsq0 = 0.f, lsum1 = 0.f, lsq1 = 0.f;

  int base = wi * 4;
  if (base < N) {
    int vend = (base + 4 < N) ? base + 4 : N;
    int nv = vend - base;
    int rpi = base + lane; if (rpi > vend) rpi = vend;
    int rp_l = rp[rpi];
    int dvi = base + (lane & 3); if (dvi >= N) dvi = N - 1;
    float dv_l = dinv[dvi];

    int e0 = __shfl(rp_l, 0, 64);
    int e1 = __shfl(rp_l, nv, 64);
    int j = 0, v = base;
    int end_cur = __shfl(rp_l, 1, 64);
    float dv = __shfl(dv_l, 0, 64);
    float acc0 = 0.f, acc1 = 0.f;
    int e = e0;
    int nb8 = (e1 - e0) >> 3;        // exact: padded segments are x8

#define FLUSHN() do { \
    float a0 = fmaxf(dv * acc0 + b0, 0.f); \
    float a1 = fmaxf(dv * acc1 + b1, 0.f); \
    uint wpk = pk_bf16(a0, a1); \
    a[(size_t)v * 64 + lane] = wpk; \
    float r0 = BLO(wpk), r1 = BHI(wpk); \
    lsum0 += r0; lsq0 += r0 * r0; lsum1 += r1; lsq1 += r1 * r1; \
    ++v; ++j; \
    if (v < vend) { \
      end_cur = __shfl(rp_l, j + 1, 64); \
      dv = __shfl(dv_l, j, 64); \
      acc0 = 0.f; acc1 = 0.f; \
    } \
  } while (0)

#define COL16(off) col[(off) + (lane & 15)]
#define GATHER(W, CU, HALF) do { \
    _Pragma("unroll") \
    for (int jj = 0; jj < 8; ++jj) { \
      int u = __shfl((int)(CU), (HALF) * 8 + jj, 64); \
      W[jj] = ms[(size_t)u * 64 + lane]; \
    } \
  } while (0)
#define STEP(W) do { \
    _Pragma("unroll") \
    for (int jj = 0; jj < 8; ++jj) { acc0 += BLO(W[jj]); acc1 += BHI(W[jj]); } \
    e += 8; \
    if (e == end_cur) FLUSHN(); \
  } while (0)

    uint cu0 = 0, cu1 = 0, cu2 = 0;
    uint w0[8], w1[8], w2[8];
    cu0 = COL16(e0);                               // batches 0,1
    if (nb8 > 2) cu1 = COL16(e0 + 16);             // batches 2,3
    GATHER(w0, cu0, 0);                            // batch 0
    if (nb8 > 1) GATHER(w1, cu0, 1);               // batch 1

    for (int k = 0; k < nb8; k += 6) {
      if (k + 4 < nb8) cu2 = COL16(e0 + (k + 4) * 8);   // batches k+4,k+5
      if (k + 2 < nb8) GATHER(w2, cu1, 0);              // batch k+2
      STEP(w0);                                          // batch k
      if (k + 3 < nb8) GATHER(w0, cu1, 1);              // batch k+3
      if (k + 1 < nb8) STEP(w1);                        // batch k+1
      if (k + 6 < nb8) cu0 = COL16(e0 + (k + 6) * 8);   // batches k+6,k+7
      if (k + 4 < nb8) GATHER(w1, cu2, 0);              // batch k+4
      if (k + 2 < nb8) STEP(w2);                        // batch k+2
      if (k + 5 < nb8) GATHER(w2, cu2, 1);              // batch k+5
      if (k + 3 < nb8) STEP(w0);                        // batch k+3
      if (k + 8 < nb8) cu1 = COL16(e0 + (k + 8) * 8);   // batches k+8,k+9
      if (k + 6 < nb8) GATHER(w0, cu0, 0);              // batch k+6
      if (k + 4 < nb8) STEP(w1);                        // batch k+4
      if (k + 7 < nb8) GATHER(w1, cu0, 1);              // batch k+7
      if (k + 5 < nb8) STEP(w2);                        // batch k+5
    }
#undef FLUSHN
#undef COL16
#undef GATHER
#undef STEP
  }

  atomicAdd(&s_sum[2 * lane], lsum0);
  atomicAdd(&s_sum[2 * lane + 1], lsum1);
  atomicAdd(&s_sq[2 * lane], lsq0);
  atomicAdd(&s_sq[2 * lane + 1], lsq1);
  __syncthreads();
  for (int i = threadIdx.x; i < 128; i += 256) {
    atomicAdd(&bn_sum[i], s_sum[i]);
    atomicAdd(&bn_sq[i], s_sq[i]);
  }
}

// ------- fused readout: one wave per graph, BN(fold in-lane)+relu+res+mean ---
__global__ __launch_bounds__(256) void k_poolout(const uint* __restrict__ a,
    const uint* __restrict__ hold,
    const float* __restrict__ bn_sum, const float* __restrict__ bn_sq,
    const float* __restrict__ gamma, const float* __restrict__ beta,
    const int* __restrict__ gstart,
    const float* __restrict__ lw, const float* __restrict__ lb,
    float* __restrict__ out, int G, float invN) {
  int g = (blockIdx.x * 256 + threadIdx.x) >> 6;
  int lane = threadIdx.x & 63;
  if (g >= G) return;
  float2 su = *(const float2*)(bn_sum + 2 * lane);
  float2 sq = *(const float2*)(bn_sq + 2 * lane);
  float2 gm = *(const float2*)(gamma + 2 * lane);
  float2 bt = *(const float2*)(beta + 2 * lane);
  float m0 = su.x * invN, m1 = su.y * invN;
  float sc0 = gm.x * rsqrtf(sq.x * invN - m0 * m0 + 1e-5f);
  float sc1 = gm.y * rsqrtf(sq.y * invN - m1 * m1 + 1e-5f);
  float bb0 = bt.x - m0 * sc0, bb1 = bt.y - m1 * sc1;
  int s0 = gstart[g], s1 = gstart[g + 1];
  float acc0 = 0.f, acc1 = 0.f;
  for (int v = s0; v < s1; ++v) {
    uint av = a[(size_t)v * 64 + lane];
    uint hv = hold[(size_t)v * 64 + lane];
    acc0 += fmaxf(sc0 * BLO(av) + bb0, 0.f) + BLO(hv);
    acc1 += fmaxf(sc1 * BHI(av) + bb1, 0.f) + BHI(hv);
  }
  float inv = 1.f / fmaxf((float)(s1 - s0), 1.f);
  float2 w2 = *(const float2*)(lw + 2 * lane);
  float s = acc0 * inv * w2.x + acc1 * inv * w2.y;
#pragma unroll
  for (int off = 32; off > 0; off >>= 1) s += __shfl_down(s, off, 64);
  if (lane == 0) out[g] = 1.f / (1.f + expf(-(s + lb[0])));
}

extern "C" void kernel_launch(void* const* d_in, const int* in_sizes, int n_in,
                              void* d_out, int out_size, void* d_ws, size_t ws_size,
                              hipStream_t stream) {
  const int* x      = (const int*)d_in[0];
  const int* ei     = (const int*)d_in[1];
  const int* batch  = (const int*)d_in[2];
  const float* emb  = (const float*)d_in[3];
  const float* convW = (const float*)d_in[4];
  const float* convB = (const float*)d_in[5];
  const float* gamma = (const float*)d_in[6];
  const float* beta  = (const float*)d_in[7];
  const float* lw    = (const float*)d_in[8];
  const float* lb    = (const float*)d_in[9];
  float* out = (float*)d_out;

  const int N = in_sizes[2];
  const int E = in_sizes[1] / 2;
  const int G = out_size;
  const int MAXV = in_sizes[3] / (FEAT * H);
  const int L = in_sizes[4] / (H * H);
  const int Npad = (N + 128) & ~127;     // guarantees zero row N exists

  const int* srcp = ei;
  const int* dstp = ei + E;

  char* p = (char*)d_ws;
  auto alloc = [&](size_t bytes) { char* r = p; p += (bytes + 255) & ~255ull; return r; };
  uint*  h    = (uint*)alloc((size_t)Npad * 64 * 4);   // bf16x2 packed residual
  uint*  ms   = (uint*)alloc((size_t)Npad * 64 * 4);   // bf16x2 packed, pre-scaled
  uint*  a    = (uint*)alloc((size_t)Npad * 64 * 4);   // bf16x2 packed activations
  float* dinv = (float*)alloc((size_t)N * 4);
  int* row_ptr = (int*)alloc((size_t)(N + 1) * 4);
  int* col     = (int*)alloc(((size_t)E + 8 * (size_t)N + 64) * 4);  // padded CSR
  int* pcnt    = (int*)alloc((size_t)N * 4);
  int* incl    = (int*)alloc((size_t)N * 4);
  int* bsum    = (int*)alloc(256 * 4);
  uint* wt     = (uint*)alloc((size_t)L * H * 64 * 4); // WT bf16 [l][n][k/2]
  int* gstart  = (int*)alloc((size_t)(G + 1) * 4);
  char* z0 = p;
  int* counts   = (int*)alloc((size_t)N * 4);
  int* cursor   = (int*)alloc((size_t)N * 4);
  float* bn_sum = (float*)alloc((size_t)L * H * 4);
  float* bn_sq  = (float*)alloc((size_t)L * H * 4);
  size_t zbytes = (size_t)(p - z0);

  hipMemsetAsync(z0, 0, zbytes, stream);
  // a rows [N, Npad): finite garbage is OK but zero for cleanliness
  hipMemsetAsync(a + (size_t)N * 64, 0, (size_t)(Npad - N) * 256, stream);

  const int nb = (N + 255) / 256;
  const float invN = 1.0f / (float)N;

  // graph prep
  k_atom<<<Npad / 4, 256, 0, stream>>>(x, emb, h, N, Npad, MAXV);
  k_count<<<(E + 255) / 256, 256, 0, stream>>>(dstp, counts, E);
  k_dinv<<<(N + 255) / 256, 256, 0, stream>>>(counts, dinv, pcnt, N);
  k_scan1<<<nb, 256, 0, stream>>>(pcnt, incl, bsum, N);
  k_scan2<<<1, 256, 0, stream>>>(bsum, nb);
  k_scan3<<<nb, 256, 0, stream>>>(incl, bsum, row_ptr, N);
  k_fill<<<(E + 255) / 256, 256, 0, stream>>>(srcp, dstp, row_ptr, cursor, col, E);
  k_pad<<<nb, 256, 0, stream>>>(counts, row_ptr, col, N);
  k_bound<<<(N + 256) / 256, 256, 0, stream>>>(batch, gstart, N, G);
  k_wt<<<(L * H * 64 + 255) / 256, 256, 0, stream>>>(convW, wt, L * H * 64);

  const int aggWaves = (N + 3) / 4;
  const int aggBlocks = (aggWaves + 3) / 4;

  // layers
  for (int l = 0; l < L; ++l) {
    if (l == 0) {
      k_gemm_mfma<0><<<Npad / 128, 256, 0, stream>>>(
          h, nullptr, nullptr, nullptr, nullptr, nullptr, nullptr, 0.f,
          wt, ms, dinv, N);
    } else {
      k_gemm_mfma<1><<<Npad / 128, 256, 0, stream>>>(
          a, h, h,
          bn_sum + (size_t)(l - 1) * H, bn_sq + (size_t)(l - 1) * H,
          gamma + (size_t)(l - 1) * H, beta + (size_t)(l - 1) * H, invN,
          wt + (size_t)l * H * 64, ms, dinv, N);
    }
    k_agg<<<aggBlocks, 256, 0, stream>>>(ms, row_ptr, col, dinv, convB + (size_t)l * H,
                                         a, bn_sum + (size_t)l * H, bn_sq + (size_t)l * H, N);
  }

  // fused readout (final BN fold + relu + residual + mean-pool + linear + sigmoid)
  k_poolout<<<(G + 3) / 4, 256, 0, stream>>>(
      a, h, bn_sum + (size_t)(L - 1) * H, bn_sq + (size_t)(L - 1) * H,
      gamma + (size_t)(L - 1) * H, beta + (size_t)(L - 1) * H,
      gstart, lw, lb, out, G, invN);
}

// Round 10
// 478.897 us; speedup vs baseline: 1.2181x; 1.2181x over previous
//
#include <hip/hip_runtime.h>
#include <hip/hip_bf16.h>
#include <math.h>

#define H 128
#define FEAT 9

typedef unsigned int uint;
typedef __attribute__((ext_vector_type(8))) short short8;   // 8 bf16 = 4 VGPR
typedef __attribute__((ext_vector_type(4))) float f32x4;

// round-to-nearest-even f32 -> bf16 (finite inputs)
__device__ inline uint f2bf(float f) {
  uint u = __float_as_uint(f);
  return (u + 0x7FFF + ((u >> 16) & 1)) >> 16;
}
__device__ inline uint pk_bf16(float a, float b) {
  return f2bf(a) | (f2bf(b) << 16);
}
#define BLO(u) __uint_as_float((u) << 16)
#define BHI(u) __uint_as_float((u) & 0xFFFF0000u)

// ---------------- Atom encoder: h[v] = bf16x2(sum_f emb[f, x[v,f], :]) -------
__global__ __launch_bounds__(256) void k_atom(const int* __restrict__ x,
    const float* __restrict__ emb, uint* __restrict__ h,
    int N, int Npad, int maxv) {
  int wid = (blockIdx.x * blockDim.x + threadIdx.x) >> 6;
  int lane = threadIdx.x & 63;
  if (wid >= Npad) return;
  float a0 = 0.f, a1 = 0.f;
  if (wid < N) {
    const int* xr = x + (size_t)wid * FEAT;
#pragma unroll
    for (int f = 0; f < FEAT; ++f) {
      int id = xr[f];
      float2 e2 = *(const float2*)(emb + ((size_t)f * maxv + id) * H + 2 * lane);
      a0 += e2.x; a1 += e2.y;
    }
  }
  h[(size_t)wid * 64 + lane] = pk_bf16(a0, a1);
}

// ---------------- degree count (by dst) ----------------
__global__ __launch_bounds__(256) void k_count(const int* __restrict__ dst,
    int* __restrict__ counts, int E) {
  int i = blockIdx.x * blockDim.x + threadIdx.x;
  if (i < E) atomicAdd(&counts[dst[i]], 1);
}

// dinv + padded counts: degree+1 (self edge) padded to multiple of 8
__global__ __launch_bounds__(256) void k_dinv(const int* __restrict__ counts,
    float* __restrict__ dinv, int* __restrict__ pcnt, int N) {
  int i = blockIdx.x * blockDim.x + threadIdx.x;
  if (i < N) {
    int c = counts[i];
    dinv[i] = rsqrtf((float)(c + 1));
    pcnt[i] = (c + 8) & ~7;          // >= c+1, multiple of 8, min 8
  }
}

// ---------------- hierarchical scan (over padded counts) ----------------
__global__ __launch_bounds__(256) void k_scan1(const int* __restrict__ counts,
    int* __restrict__ incl, int* __restrict__ bsum, int n) {
  __shared__ int ws[4];
  int t = threadIdx.x;
  int i = blockIdx.x * 256 + t;
  int lane = t & 63, w = t >> 6;
  int v = (i < n) ? counts[i] : 0;
  int s = v;
#pragma unroll
  for (int off = 1; off < 64; off <<= 1) {
    int u = __shfl_up(s, off, 64);
    if (lane >= off) s += u;
  }
  if (lane == 63) ws[w] = s;
  __syncthreads();
  if (t == 0) {
    int acc = 0;
#pragma unroll
    for (int j = 0; j < 4; ++j) { int tmp = ws[j]; ws[j] = acc; acc += tmp; }
  }
  __syncthreads();
  s += ws[w];
  if (i < n) incl[i] = s;
  if (t == 255) bsum[blockIdx.x] = s;
}

__global__ __launch_bounds__(256) void k_scan2(int* __restrict__ bsum, int nb) {
  __shared__ int ws[4];
  int t = threadIdx.x, lane = t & 63, w = t >> 6;
  int v = (t < nb) ? bsum[t] : 0;
  int s = v;
#pragma unroll
  for (int off = 1; off < 64; off <<= 1) {
    int u = __shfl_up(s, off, 64);
    if (lane >= off) s += u;
  }
  if (lane == 63) ws[w] = s;
  __syncthreads();
  if (t == 0) {
    int acc = 0;
#pragma unroll
    for (int j = 0; j < 4; ++j) { int tmp = ws[j]; ws[j] = acc; acc += tmp; }
  }
  __syncthreads();
  s += ws[w];
  if (t < nb) bsum[t] = s - v;   // exclusive
}

// scan3 + pad fill fused: writes row_ptr AND the self-edge/sentinel pad region.
// Pad region [rp[v]+deg, rp[v+1]) is disjoint from k_fill's region, so order
// with k_fill is irrelevant.
__global__ __launch_bounds__(256) void k_scan3(const int* __restrict__ incl,
    const int* __restrict__ boff, const int* __restrict__ counts,
    int* __restrict__ row_ptr, int* __restrict__ col, int n, int N) {
  int i = blockIdx.x * 256 + threadIdx.x;
  if (i >= n) return;
  int end = incl[i] + boff[i >> 8];
  int start = (i == 0) ? 0 : incl[i - 1] + boff[(i - 1) >> 8];
  row_ptr[i + 1] = end;
  if (i == 0) row_ptr[0] = 0;
  int s = start + counts[i];
  col[s] = i;                               // self-loop as a real edge
  for (int k = s + 1; k < end; ++k) col[k] = N;
}

// ---------------- CSR fill (into padded layout) ----------------
__global__ __launch_bounds__(256) void k_fill(const int* __restrict__ src,
    const int* __restrict__ dst, const int* __restrict__ row_ptr,
    int* __restrict__ cursor, int* __restrict__ col, int E) {
  int i = blockIdx.x * blockDim.x + threadIdx.x;
  if (i < E) {
    int d = dst[i];
    int pos = atomicAdd(&cursor[d], 1);
    col[row_ptr[d] + pos] = src[i];
  }
}

// ---------------- graph boundaries ----------------
__global__ __launch_bounds__(256) void k_bound(const int* __restrict__ batch,
    int* __restrict__ gstart, int N, int G) {
  int i = blockIdx.x * 256 + threadIdx.x;
  if (i > N) return;
  int lo = (i == 0) ? 0 : batch[i - 1] + 1;
  int hi = (i == N) ? G : batch[i];
  for (int g = lo; g <= hi; ++g) gstart[g] = i;
}

// ---------------- W transpose + bf16: wt[l][n][k] packed pairs ----------------
__global__ __launch_bounds__(256) void k_wt(const float* __restrict__ W,
    uint* __restrict__ wt, int total) {   // total = L*128*64
  int idx = blockIdx.x * 256 + threadIdx.x;
  if (idx >= total) return;
  int l = idx >> 13;
  int rem = idx & 8191;
  int n = rem >> 6;
  int k2 = rem & 63;
  const float* w = W + (size_t)l * H * H;
  float x0 = w[(size_t)(2 * k2) * H + n];
  float x1 = w[(size_t)(2 * k2 + 1) * H + n];
  wt[idx] = pk_bf16(x0, x1);
}

// ---------------- MFMA GEMM: ms = bf16(dinv * (A' @ W)) ----------------
// FUSED: A' = relu(sc*a+bb)+hold (BN fold computed in-block), written to Hnew.
// All node tensors packed bf16x2. 128x128 tile, 4 waves, XOR-swizzled LDS.
template <int FUSED>
__global__ __launch_bounds__(256) void k_gemm_mfma(
    const uint* __restrict__ Ap, const uint* __restrict__ Hp,
    uint* __restrict__ Hnew,
    const float* __restrict__ bn_sum, const float* __restrict__ bn_sq,
    const float* __restrict__ gamma, const float* __restrict__ beta,
    float invN,
    const uint* __restrict__ wt, uint* __restrict__ ms,
    const float* __restrict__ dinv, int N) {
  __shared__ uint4 smem4[4096];          // 64 KB: sA [0,32K), sB [32K,64K)
  __shared__ float scbb[256];
  char* smemc = (char*)smem4;
  int t = threadIdx.x;
  int row0 = blockIdx.x * 128;

  if (FUSED) {
    if (t < 128) {
      float mean = bn_sum[t] * invN;
      float var = bn_sq[t] * invN - mean * mean;
      float s = gamma[t] * rsqrtf(var + 1e-5f);
      scbb[t] = s;
      scbb[128 + t] = beta[t] - mean * s;
    }
    __syncthreads();
  }

  // ---- stage A (packed bf16 source), swizzled ----
#pragma unroll
  for (int it = 0; it < 8; ++it) {
    int i = t + it * 256;                 // uint4 slots over [128][16]
    int r = i >> 4;
    int c16 = i & 15;
    uint4 w4;
    if (FUSED) {
      uint4 av = *(const uint4*)(Ap + (size_t)(row0 + r) * 64 + c16 * 4);
      uint4 hv = *(const uint4*)(Hp + (size_t)(row0 + r) * 64 + c16 * 4);
      int c0 = c16 * 8;
      float4 s0 = *(const float4*)(scbb + c0);
      float4 s1 = *(const float4*)(scbb + c0 + 4);
      float4 b0 = *(const float4*)(scbb + 128 + c0);
      float4 b1 = *(const float4*)(scbb + 128 + c0 + 4);
      float n0 = fmaxf(s0.x * BLO(av.x) + b0.x, 0.f) + BLO(hv.x);
      float n1 = fmaxf(s0.y * BHI(av.x) + b0.y, 0.f) + BHI(hv.x);
      float n2 = fmaxf(s0.z * BLO(av.y) + b0.z, 0.f) + BLO(hv.y);
      float n3 = fmaxf(s0.w * BHI(av.y) + b0.w, 0.f) + BHI(hv.y);
      float n4 = fmaxf(s1.x * BLO(av.z) + b1.x, 0.f) + BLO(hv.z);
      float n5 = fmaxf(s1.y * BHI(av.z) + b1.y, 0.f) + BHI(hv.z);
      float n6 = fmaxf(s1.z * BLO(av.w) + b1.z, 0.f) + BLO(hv.w);
      float n7 = fmaxf(s1.w * BHI(av.w) + b1.w, 0.f) + BHI(hv.w);
      w4.x = pk_bf16(n0, n1); w4.y = pk_bf16(n2, n3);
      w4.z = pk_bf16(n4, n5); w4.w = pk_bf16(n6, n7);
      *(uint4*)(Hnew + (size_t)(row0 + r) * 64 + c16 * 4) = w4;
    } else {
      w4 = *(const uint4*)(Ap + (size_t)(row0 + r) * 64 + c16 * 4);
    }
    int byte = r * 256 + ((c16 * 16) ^ ((r & 7) << 4));
    *(uint4*)(smemc + byte) = w4;
  }
  // ---- stage B: wt bf16 [n][k], swizzled ----
#pragma unroll
  for (int it = 0; it < 8; ++it) {
    int i = t + it * 256;                 // uint4 slots over [128][16]
    int n = i >> 4;
    int k16 = i & 15;
    int byte = 32768 + n * 256 + ((k16 * 16) ^ ((n & 7) << 4));
    *(uint4*)(smemc + byte) = ((const uint4*)wt)[i];
  }
  __syncthreads();

  int wid = t >> 6, l = t & 63;
  int wm = wid >> 1, wn = wid & 1;
  int lr = l & 15, lg = l >> 4;           // frag row/col, k-group

  f32x4 acc[4][4];
#pragma unroll
  for (int mt = 0; mt < 4; ++mt)
#pragma unroll
    for (int nt = 0; nt < 4; ++nt) acc[mt][nt] = (f32x4)0.f;

#pragma unroll
  for (int kk = 0; kk < 4; ++kk) {
    int kbyte = kk * 64 + lg * 16;
    short8 af[4], bf[4];
#pragma unroll
    for (int mt = 0; mt < 4; ++mt) {
      int r = wm * 64 + mt * 16 + lr;
      af[mt] = *(const short8*)(smemc + r * 256 + (kbyte ^ ((r & 7) << 4)));
    }
#pragma unroll
    for (int nt = 0; nt < 4; ++nt) {
      int n = wn * 64 + nt * 16 + lr;
      bf[nt] = *(const short8*)(smemc + 32768 + n * 256 + (kbyte ^ ((n & 7) << 4)));
    }
#pragma unroll
    for (int mt = 0; mt < 4; ++mt)
#pragma unroll
      for (int nt = 0; nt < 4; ++nt)
        acc[mt][nt] = __builtin_amdgcn_mfma_f32_16x16x32_bf16(
            af[mt], bf[nt], acc[mt][nt], 0, 0, 0);
  }
  __syncthreads();   // all LDS reads done; sA space becomes sC

  // ---- epilogue: scale by dinv, bf16, bounce through LDS, coalesced out ----
  float dr[4][4];
#pragma unroll
  for (int mt = 0; mt < 4; ++mt)
#pragma unroll
    for (int j = 0; j < 4; ++j) {
      int grow = row0 + wm * 64 + mt * 16 + lg * 4 + j;
      dr[mt][j] = (grow < N) ? dinv[grow] : 0.f;
    }
#pragma unroll
  for (int mt = 0; mt < 4; ++mt)
#pragma unroll
    for (int nt = 0; nt < 4; ++nt)
#pragma unroll
      for (int j = 0; j < 4; ++j) {
        int lrow = wm * 64 + mt * 16 + lg * 4 + j;
        int lcol = wn * 64 + nt * 16 + lr;
        float val = acc[mt][nt][j] * dr[mt][j];
        *(short*)(smemc + lrow * 256 + lcol * 2) = (short)f2bf(val);
      }
  __syncthreads();
#pragma unroll
  for (int it = 0; it < 8; ++it) {
    int i = t + it * 256;                 // uint4 slots over [128][16]
    int r = i >> 4;
    int c16 = i & 15;
    uint4 v = *(const uint4*)(smemc + r * 256 + c16 * 16);
    ((uint4*)ms)[(size_t)(row0 + r) * 16 + c16] = v;
  }
}

// ------------- aggregate v7: R7 geometry (8 nodes/wave) + self-edge ----------
// 1 dword/lane per edge = one coalesced 256B row per instruction. Self-loop is
// a real padded edge. col in 16-wide chunks 2 ahead (mod-3), 3 gather slots.
__global__ __launch_bounds__(256) void k_agg(const uint* __restrict__ ms,
    const int* __restrict__ rp, const int* __restrict__ col,
    const float* __restrict__ dinv, const float* __restrict__ bias,
    uint* __restrict__ a, float* __restrict__ bn_sum, float* __restrict__ bn_sq,
    int N) {
  __shared__ float s_sum[128], s_sq[128];
  for (int i = threadIdx.x; i < 128; i += 256) { s_sum[i] = 0.f; s_sq[i] = 0.f; }
  __syncthreads();
  int lane = threadIdx.x & 63;
  int wi = (blockIdx.x * 256 + threadIdx.x) >> 6;
  float b0 = bias[2 * lane], b1 = bias[2 * lane + 1];
  float lsum0 = 0.f, lsq0 = 0.f, lsum1 = 0.f, lsq1 = 0.f;

  int base = wi * 8;
  if (base < N) {
    int vend = (base + 8 < N) ? base + 8 : N;
    int nv = vend - base;
    int rpi = base + lane; if (rpi > vend) rpi = vend;
    int rp_l = rp[rpi];
    int dvi = base + (lane & 7); if (dvi >= N) dvi = N - 1;
    float dv_l = dinv[dvi];

    int e0 = __shfl(rp_l, 0, 64);
    int e1 = __shfl(rp_l, nv, 64);
    int j = 0, v = base;
    int end_cur = __shfl(rp_l, 1, 64);
    float dv = __shfl(dv_l, 0, 64);
    float acc0 = 0.f, acc1 = 0.f;
    int e = e0;
    int nb8 = (e1 - e0) >> 3;        // exact: padded segments are x8

#define FLUSHN() do { \
    float a0 = fmaxf(dv * acc0 + b0, 0.f); \
    float a1 = fmaxf(dv * acc1 + b1, 0.f); \
    uint wpk = pk_bf16(a0, a1); \
    a[(size_t)v * 64 + lane] = wpk; \
    float r0 = BLO(wpk), r1 = BHI(wpk); \
    lsum0 += r0; lsq0 += r0 * r0; lsum1 += r1; lsq1 += r1 * r1; \
    ++v; ++j; \
    if (v < vend) { \
      end_cur = __shfl(rp_l, j + 1, 64); \
      dv = __shfl(dv_l, j, 64); \
      acc0 = 0.f; acc1 = 0.f; \
    } \
  } while (0)

#define COL16(off) col[(off) + (lane & 15)]
#define GATHER(W, CU, HALF) do { \
    _Pragma("unroll") \
    for (int jj = 0; jj < 8; ++jj) { \
      int u = __shfl((int)(CU), (HALF) * 8 + jj, 64); \
      W[jj] = ms[(size_t)u * 64 + lane]; \
    } \
  } while (0)
#define STEP(W) do { \
    _Pragma("unroll") \
    for (int jj = 0; jj < 8; ++jj) { acc0 += BLO(W[jj]); acc1 += BHI(W[jj]); } \
    e += 8; \
    if (e == end_cur) FLUSHN(); \
  } while (0)

    uint cu0 = 0, cu1 = 0, cu2 = 0;
    uint w0[8], w1[8], w2[8];
    cu0 = COL16(e0);                               // batches 0,1
    if (nb8 > 2) cu1 = COL16(e0 + 16);             // batches 2,3
    GATHER(w0, cu0, 0);                            // batch 0
    if (nb8 > 1) GATHER(w1, cu0, 1);               // batch 1

    for (int k = 0; k < nb8; k += 6) {
      if (k + 4 < nb8) cu2 = COL16(e0 + (k + 4) * 8);   // batches k+4,k+5
      if (k + 2 < nb8) GATHER(w2, cu1, 0);              // batch k+2
      STEP(w0);                                          // batch k
      if (k + 3 < nb8) GATHER(w0, cu1, 1);              // batch k+3
      if (k + 1 < nb8) STEP(w1);                        // batch k+1
      if (k + 6 < nb8) cu0 = COL16(e0 + (k + 6) * 8);   // batches k+6,k+7
      if (k + 4 < nb8) GATHER(w1, cu2, 0);              // batch k+4
      if (k + 2 < nb8) STEP(w2);                        // batch k+2
      if (k + 5 < nb8) GATHER(w2, cu2, 1);              // batch k+5
      if (k + 3 < nb8) STEP(w0);                        // batch k+3
      if (k + 8 < nb8) cu1 = COL16(e0 + (k + 8) * 8);   // batches k+8,k+9
      if (k + 6 < nb8) GATHER(w0, cu0, 0);              // batch k+6
      if (k + 4 < nb8) STEP(w1);                        // batch k+4
      if (k + 7 < nb8) GATHER(w1, cu0, 1);              // batch k+7
      if (k + 5 < nb8) STEP(w2);                        // batch k+5
    }
#undef FLUSHN
#undef COL16
#undef GATHER
#undef STEP
  }

  atomicAdd(&s_sum[2 * lane], lsum0);
  atomicAdd(&s_sum[2 * lane + 1], lsum1);
  atomicAdd(&s_sq[2 * lane], lsq0);
  atomicAdd(&s_sq[2 * lane + 1], lsq1);
  __syncthreads();
  for (int i = threadIdx.x; i < 128; i += 256) {
    atomicAdd(&bn_sum[i], s_sum[i]);
    atomicAdd(&bn_sq[i], s_sq[i]);
  }
}

// ------- fused readout: one wave per graph, BN(fold in-lane)+relu+res+mean ---
__global__ __launch_bounds__(256) void k_poolout(const uint* __restrict__ a,
    const uint* __restrict__ hold,
    const float* __restrict__ bn_sum, const float* __restrict__ bn_sq,
    const float* __restrict__ gamma, const float* __restrict__ beta,
    const int* __restrict__ gstart,
    const float* __restrict__ lw, const float* __restrict__ lb,
    float* __restrict__ out, int G, float invN) {
  int g = (blockIdx.x * 256 + threadIdx.x) >> 6;
  int lane = threadIdx.x & 63;
  if (g >= G) return;
  float2 su = *(const float2*)(bn_sum + 2 * lane);
  float2 sq = *(const float2*)(bn_sq + 2 * lane);
  float2 gm = *(const float2*)(gamma + 2 * lane);
  float2 bt = *(const float2*)(beta + 2 * lane);
  float m0 = su.x * invN, m1 = su.y * invN;
  float sc0 = gm.x * rsqrtf(sq.x * invN - m0 * m0 + 1e-5f);
  float sc1 = gm.y * rsqrtf(sq.y * invN - m1 * m1 + 1e-5f);
  float bb0 = bt.x - m0 * sc0, bb1 = bt.y - m1 * sc1;
  int s0 = gstart[g], s1 = gstart[g + 1];
  float acc0 = 0.f, acc1 = 0.f;
  for (int v = s0; v < s1; ++v) {
    uint av = a[(size_t)v * 64 + lane];
    uint hv = hold[(size_t)v * 64 + lane];
    acc0 += fmaxf(sc0 * BLO(av) + bb0, 0.f) + BLO(hv);
    acc1 += fmaxf(sc1 * BHI(av) + bb1, 0.f) + BHI(hv);
  }
  float inv = 1.f / fmaxf((float)(s1 - s0), 1.f);
  float2 w2 = *(const float2*)(lw + 2 * lane);
  float s = acc0 * inv * w2.x + acc1 * inv * w2.y;
#pragma unroll
  for (int off = 32; off > 0; off >>= 1) s += __shfl_down(s, off, 64);
  if (lane == 0) out[g] = 1.f / (1.f + expf(-(s + lb[0])));
}

extern "C" void kernel_launch(void* const* d_in, const int* in_sizes, int n_in,
                              void* d_out, int out_size, void* d_ws, size_t ws_size,
                              hipStream_t stream) {
  const int* x      = (const int*)d_in[0];
  const int* ei     = (const int*)d_in[1];
  const int* batch  = (const int*)d_in[2];
  const float* emb  = (const float*)d_in[3];
  const float* convW = (const float*)d_in[4];
  const float* convB = (const float*)d_in[5];
  const float* gamma = (const float*)d_in[6];
  const float* beta  = (const float*)d_in[7];
  const float* lw    = (const float*)d_in[8];
  const float* lb    = (const float*)d_in[9];
  float* out = (float*)d_out;

  const int N = in_sizes[2];
  const int E = in_sizes[1] / 2;
  const int G = out_size;
  const int MAXV = in_sizes[3] / (FEAT * H);
  const int L = in_sizes[4] / (H * H);
  const int Npad = (N + 128) & ~127;     // guarantees zero row N exists

  const int* srcp = ei;
  const int* dstp = ei + E;

  char* p = (char*)d_ws;
  auto alloc = [&](size_t bytes) { char* r = p; p += (bytes + 255) & ~255ull; return r; };
  uint*  h    = (uint*)alloc((size_t)Npad * 64 * 4);   // bf16x2 packed residual
  uint*  ms   = (uint*)alloc((size_t)Npad * 64 * 4);   // bf16x2 packed, pre-scaled
  uint*  a    = (uint*)alloc((size_t)Npad * 64 * 4);   // bf16x2 packed activations
  float* dinv = (float*)alloc((size_t)N * 4);
  int* row_ptr = (int*)alloc((size_t)(N + 1) * 4);
  int* col     = (int*)alloc(((size_t)E + 8 * (size_t)N + 64) * 4);  // padded CSR
  int* pcnt    = (int*)alloc((size_t)N * 4);
  int* incl    = (int*)alloc((size_t)N * 4);
  int* bsum    = (int*)alloc(256 * 4);
  uint* wt     = (uint*)alloc((size_t)L * H * 64 * 4); // WT bf16 [l][n][k/2]
  int* gstart  = (int*)alloc((size_t)(G + 1) * 4);
  char* z0 = p;
  int* counts   = (int*)alloc((size_t)N * 4);
  int* cursor   = (int*)alloc((size_t)N * 4);
  float* bn_sum = (float*)alloc((size_t)L * H * 4);
  float* bn_sq  = (float*)alloc((size_t)L * H * 4);
  size_t zbytes = (size_t)(p - z0);

  hipMemsetAsync(z0, 0, zbytes, stream);
  // a rows [N, Npad): finite garbage is OK but zero for cleanliness
  hipMemsetAsync(a + (size_t)N * 64, 0, (size_t)(Npad - N) * 256, stream);

  const int nb = (N + 255) / 256;
  const float invN = 1.0f / (float)N;

  // graph prep
  k_atom<<<Npad / 4, 256, 0, stream>>>(x, emb, h, N, Npad, MAXV);
  k_count<<<(E + 255) / 256, 256, 0, stream>>>(dstp, counts, E);
  k_dinv<<<(N + 255) / 256, 256, 0, stream>>>(counts, dinv, pcnt, N);
  k_scan1<<<nb, 256, 0, stream>>>(pcnt, incl, bsum, N);
  k_scan2<<<1, 256, 0, stream>>>(bsum, nb);
  k_scan3<<<nb, 256, 0, stream>>>(incl, bsum, counts, row_ptr, col, N, N);
  k_fill<<<(E + 255) / 256, 256, 0, stream>>>(srcp, dstp, row_ptr, cursor, col, E);
  k_bound<<<(N + 256) / 256, 256, 0, stream>>>(batch, gstart, N, G);
  k_wt<<<(L * H * 64 + 255) / 256, 256, 0, stream>>>(convW, wt, L * H * 64);

  const int aggWaves = (N + 7) / 8;
  const int aggBlocks = (aggWaves + 3) / 4;

  // layers
  for (int l = 0; l < L; ++l) {
    if (l == 0) {
      k_gemm_mfma<0><<<Npad / 128, 256, 0, stream>>>(
          h, nullptr, nullptr, nullptr, nullptr, nullptr, nullptr, 0.f,
          wt, ms, dinv, N);
    } else {
      k_gemm_mfma<1><<<Npad / 128, 256, 0, stream>>>(
          a, h, h,
          bn_sum + (size_t)(l - 1) * H, bn_sq + (size_t)(l - 1) * H,
          gamma + (size_t)(l - 1) * H, beta + (size_t)(l - 1) * H, invN,
          wt + (size_t)l * H * 64, ms, dinv, N);
    }
    k_agg<<<aggBlocks, 256, 0, stream>>>(ms, row_ptr, col, dinv, convB + (size_t)l * H,
                                         a, bn_sum + (size_t)l * H, bn_sq + (size_t)l * H, N);
  }

  // fused readout (final BN fold + relu + residual + mean-pool + linear + sigmoid)
  k_poolout<<<(G + 3) / 4, 256, 0, stream>>>(
      a, h, bn_sum + (size_t)(L - 1) * H, bn_sq + (size_t)(L - 1) * H,
      gamma + (size_t)(L - 1) * H, beta + (size_t)(L - 1) * H,
      gstart, lw, lb, out, G, invN);
}

// Round 11
// 450.491 us; speedup vs baseline: 1.2949x; 1.0631x over previous
//
#include <hip/hip_runtime.h>
#include <hip/hip_bf16.h>
#include <math.h>

#define H 128
#define FEAT 9

typedef unsigned int uint;
typedef __attribute__((ext_vector_type(8))) short short8;   // 8 bf16 = 4 VGPR
typedef __attribute__((ext_vector_type(4))) float f32x4;

// round-to-nearest-even f32 -> bf16 (finite inputs)
__device__ inline uint f2bf(float f) {
  uint u = __float_as_uint(f);
  return (u + 0x7FFF + ((u >> 16) & 1)) >> 16;
}
__device__ inline uint pk_bf16(float a, float b) {
  return f2bf(a) | (f2bf(b) << 16);
}
#define BLO(u) __uint_as_float((u) << 16)
#define BHI(u) __uint_as_float((u) & 0xFFFF0000u)

// ---------------- Atom encoder: h[v] = bf16x2(sum_f emb[f, x[v,f], :]) -------
__global__ __launch_bounds__(256) void k_atom(const int* __restrict__ x,
    const float* __restrict__ emb, uint* __restrict__ h,
    int N, int Npad, int maxv) {
  int wid = (blockIdx.x * blockDim.x + threadIdx.x) >> 6;
  int lane = threadIdx.x & 63;
  if (wid >= Npad) return;
  float a0 = 0.f, a1 = 0.f;
  if (wid < N) {
    const int* xr = x + (size_t)wid * FEAT;
#pragma unroll
    for (int f = 0; f < FEAT; ++f) {
      int id = xr[f];
      float2 e2 = *(const float2*)(emb + ((size_t)f * maxv + id) * H + 2 * lane);
      a0 += e2.x; a1 += e2.y;
    }
  }
  h[(size_t)wid * 64 + lane] = pk_bf16(a0, a1);
}

// ---------------- degree count (by dst) ----------------
__global__ __launch_bounds__(256) void k_count(const int* __restrict__ dst,
    int* __restrict__ counts, int E) {
  int i = blockIdx.x * blockDim.x + threadIdx.x;
  if (i < E) atomicAdd(&counts[dst[i]], 1);
}

// dinv + padded counts: degree padded to multiple of 8, min 8 (R7 semantics:
// self-loop handled in-register by k_agg, NOT as a stream edge)
__global__ __launch_bounds__(256) void k_dinv(const int* __restrict__ counts,
    float* __restrict__ dinv, int* __restrict__ pcnt, int N) {
  int i = blockIdx.x * blockDim.x + threadIdx.x;
  if (i < N) {
    int c = counts[i];
    dinv[i] = rsqrtf((float)(c + 1));
    int p = (c + 7) & ~7;
    pcnt[i] = (p < 8) ? 8 : p;
  }
}

// ---------------- hierarchical scan (over padded counts) ----------------
__global__ __launch_bounds__(256) void k_scan1(const int* __restrict__ counts,
    int* __restrict__ incl, int* __restrict__ bsum, int n) {
  __shared__ int ws[4];
  int t = threadIdx.x;
  int i = blockIdx.x * 256 + t;
  int lane = t & 63, w = t >> 6;
  int v = (i < n) ? counts[i] : 0;
  int s = v;
#pragma unroll
  for (int off = 1; off < 64; off <<= 1) {
    int u = __shfl_up(s, off, 64);
    if (lane >= off) s += u;
  }
  if (lane == 63) ws[w] = s;
  __syncthreads();
  if (t == 0) {
    int acc = 0;
#pragma unroll
    for (int j = 0; j < 4; ++j) { int tmp = ws[j]; ws[j] = acc; acc += tmp; }
  }
  __syncthreads();
  s += ws[w];
  if (i < n) incl[i] = s;
  if (t == 255) bsum[blockIdx.x] = s;
}

__global__ __launch_bounds__(256) void k_scan2(int* __restrict__ bsum, int nb) {
  __shared__ int ws[4];
  int t = threadIdx.x, lane = t & 63, w = t >> 6;
  int v = (t < nb) ? bsum[t] : 0;
  int s = v;
#pragma unroll
  for (int off = 1; off < 64; off <<= 1) {
    int u = __shfl_up(s, off, 64);
    if (lane >= off) s += u;
  }
  if (lane == 63) ws[w] = s;
  __syncthreads();
  if (t == 0) {
    int acc = 0;
#pragma unroll
    for (int j = 0; j < 4; ++j) { int tmp = ws[j]; ws[j] = acc; acc += tmp; }
  }
  __syncthreads();
  s += ws[w];
  if (t < nb) bsum[t] = s - v;   // exclusive
}

// scan3 + sentinel pad fused: writes row_ptr AND fills [rp[v]+deg, rp[v+1])
// with N (zero row). Disjoint from k_fill's region, so order-independent.
__global__ __launch_bounds__(256) void k_scan3(const int* __restrict__ incl,
    const int* __restrict__ boff, const int* __restrict__ counts,
    int* __restrict__ row_ptr, int* __restrict__ col, int n, int N) {
  int i = blockIdx.x * 256 + threadIdx.x;
  if (i >= n) return;
  int end = incl[i] + boff[i >> 8];
  int start = (i == 0) ? 0 : incl[i - 1] + boff[(i - 1) >> 8];
  row_ptr[i + 1] = end;
  if (i == 0) row_ptr[0] = 0;
  for (int k = start + counts[i]; k < end; ++k) col[k] = N;
}

// ---------------- CSR fill (into padded layout) ----------------
__global__ __launch_bounds__(256) void k_fill(const int* __restrict__ src,
    const int* __restrict__ dst, const int* __restrict__ row_ptr,
    int* __restrict__ cursor, int* __restrict__ col, int E) {
  int i = blockIdx.x * blockDim.x + threadIdx.x;
  if (i < E) {
    int d = dst[i];
    int pos = atomicAdd(&cursor[d], 1);
    col[row_ptr[d] + pos] = src[i];
  }
}

// ---------------- graph boundaries ----------------
__global__ __launch_bounds__(256) void k_bound(const int* __restrict__ batch,
    int* __restrict__ gstart, int N, int G) {
  int i = blockIdx.x * 256 + threadIdx.x;
  if (i > N) return;
  int lo = (i == 0) ? 0 : batch[i - 1] + 1;
  int hi = (i == N) ? G : batch[i];
  for (int g = lo; g <= hi; ++g) gstart[g] = i;
}

// ---------------- W transpose + bf16: wt[l][n][k] packed pairs ----------------
__global__ __launch_bounds__(256) void k_wt(const float* __restrict__ W,
    uint* __restrict__ wt, int total) {   // total = L*128*64
  int idx = blockIdx.x * 256 + threadIdx.x;
  if (idx >= total) return;
  int l = idx >> 13;
  int rem = idx & 8191;
  int n = rem >> 6;
  int k2 = rem & 63;
  const float* w = W + (size_t)l * H * H;
  float x0 = w[(size_t)(2 * k2) * H + n];
  float x1 = w[(size_t)(2 * k2 + 1) * H + n];
  wt[idx] = pk_bf16(x0, x1);
}

// ---------------- MFMA GEMM: ms = bf16(dinv * (A' @ W)) ----------------
// FUSED: A' = relu(sc*a+bb)+hold (BN fold computed in-block), written to Hnew.
// All node tensors packed bf16x2. 128x128 tile, 4 waves, XOR-swizzled LDS.
template <int FUSED>
__global__ __launch_bounds__(256) void k_gemm_mfma(
    const uint* __restrict__ Ap, const uint* __restrict__ Hp,
    uint* __restrict__ Hnew,
    const float* __restrict__ bn_sum, const float* __restrict__ bn_sq,
    const float* __restrict__ gamma, const float* __restrict__ beta,
    float invN,
    const uint* __restrict__ wt, uint* __restrict__ ms,
    const float* __restrict__ dinv, int N) {
  __shared__ uint4 smem4[4096];          // 64 KB: sA [0,32K), sB [32K,64K)
  __shared__ float scbb[256];
  char* smemc = (char*)smem4;
  int t = threadIdx.x;
  int row0 = blockIdx.x * 128;

  if (FUSED) {
    if (t < 128) {
      float mean = bn_sum[t] * invN;
      float var = bn_sq[t] * invN - mean * mean;
      float s = gamma[t] * rsqrtf(var + 1e-5f);
      scbb[t] = s;
      scbb[128 + t] = beta[t] - mean * s;
    }
    __syncthreads();
  }

  // ---- stage A (packed bf16 source), swizzled ----
#pragma unroll
  for (int it = 0; it < 8; ++it) {
    int i = t + it * 256;                 // uint4 slots over [128][16]
    int r = i >> 4;
    int c16 = i & 15;
    uint4 w4;
    if (FUSED) {
      uint4 av = *(const uint4*)(Ap + (size_t)(row0 + r) * 64 + c16 * 4);
      uint4 hv = *(const uint4*)(Hp + (size_t)(row0 + r) * 64 + c16 * 4);
      int c0 = c16 * 8;
      float4 s0 = *(const float4*)(scbb + c0);
      float4 s1 = *(const float4*)(scbb + c0 + 4);
      float4 b0 = *(const float4*)(scbb + 128 + c0);
      float4 b1 = *(const float4*)(scbb + 128 + c0 + 4);
      float n0 = fmaxf(s0.x * BLO(av.x) + b0.x, 0.f) + BLO(hv.x);
      float n1 = fmaxf(s0.y * BHI(av.x) + b0.y, 0.f) + BHI(hv.x);
      float n2 = fmaxf(s0.z * BLO(av.y) + b0.z, 0.f) + BLO(hv.y);
      float n3 = fmaxf(s0.w * BHI(av.y) + b0.w, 0.f) + BHI(hv.y);
      float n4 = fmaxf(s1.x * BLO(av.z) + b1.x, 0.f) + BLO(hv.z);
      float n5 = fmaxf(s1.y * BHI(av.z) + b1.y, 0.f) + BHI(hv.z);
      float n6 = fmaxf(s1.z * BLO(av.w) + b1.z, 0.f) + BLO(hv.w);
      float n7 = fmaxf(s1.w * BHI(av.w) + b1.w, 0.f) + BHI(hv.w);
      w4.x = pk_bf16(n0, n1); w4.y = pk_bf16(n2, n3);
      w4.z = pk_bf16(n4, n5); w4.w = pk_bf16(n6, n7);
      *(uint4*)(Hnew + (size_t)(row0 + r) * 64 + c16 * 4) = w4;
    } else {
      w4 = *(const uint4*)(Ap + (size_t)(row0 + r) * 64 + c16 * 4);
    }
    int byte = r * 256 + ((c16 * 16) ^ ((r & 7) << 4));
    *(uint4*)(smemc + byte) = w4;
  }
  // ---- stage B: wt bf16 [n][k], swizzled ----
#pragma unroll
  for (int it = 0; it < 8; ++it) {
    int i = t + it * 256;                 // uint4 slots over [128][16]
    int n = i >> 4;
    int k16 = i & 15;
    int byte = 32768 + n * 256 + ((k16 * 16) ^ ((n & 7) << 4));
    *(uint4*)(smemc + byte) = ((const uint4*)wt)[i];
  }
  __syncthreads();

  int wid = t >> 6, l = t & 63;
  int wm = wid >> 1, wn = wid & 1;
  int lr = l & 15, lg = l >> 4;           // frag row/col, k-group

  f32x4 acc[4][4];
#pragma unroll
  for (int mt = 0; mt < 4; ++mt)
#pragma unroll
    for (int nt = 0; nt < 4; ++nt) acc[mt][nt] = (f32x4)0.f;

#pragma unroll
  for (int kk = 0; kk < 4; ++kk) {
    int kbyte = kk * 64 + lg * 16;
    short8 af[4], bf[4];
#pragma unroll
    for (int mt = 0; mt < 4; ++mt) {
      int r = wm * 64 + mt * 16 + lr;
      af[mt] = *(const short8*)(smemc + r * 256 + (kbyte ^ ((r & 7) << 4)));
    }
#pragma unroll
    for (int nt = 0; nt < 4; ++nt) {
      int n = wn * 64 + nt * 16 + lr;
      bf[nt] = *(const short8*)(smemc + 32768 + n * 256 + (kbyte ^ ((n & 7) << 4)));
    }
#pragma unroll
    for (int mt = 0; mt < 4; ++mt)
#pragma unroll
      for (int nt = 0; nt < 4; ++nt)
        acc[mt][nt] = __builtin_amdgcn_mfma_f32_16x16x32_bf16(
            af[mt], bf[nt], acc[mt][nt], 0, 0, 0);
  }
  __syncthreads();   // all LDS reads done; sA space becomes sC

  // ---- epilogue: scale by dinv, bf16, bounce through LDS, coalesced out ----
  float dr[4][4];
#pragma unroll
  for (int mt = 0; mt < 4; ++mt)
#pragma unroll
    for (int j = 0; j < 4; ++j) {
      int grow = row0 + wm * 64 + mt * 16 + lg * 4 + j;
      dr[mt][j] = (grow < N) ? dinv[grow] : 0.f;
    }
#pragma unroll
  for (int mt = 0; mt < 4; ++mt)
#pragma unroll
    for (int nt = 0; nt < 4; ++nt)
#pragma unroll
      for (int j = 0; j < 4; ++j) {
        int lrow = wm * 64 + mt * 16 + lg * 4 + j;
        int lcol = wn * 64 + nt * 16 + lr;
        float val = acc[mt][nt][j] * dr[mt][j];
        *(short*)(smemc + lrow * 256 + lcol * 2) = (short)f2bf(val);
      }
  __syncthreads();
#pragma unroll
  for (int it = 0; it < 8; ++it) {
    int i = t + it * 256;                 // uint4 slots over [128][16]
    int r = i >> 4;
    int c16 = i & 15;
    uint4 v = *(const uint4*)(smemc + r * 256 + c16 * 16);
    ((uint4*)ms)[(size_t)(row0 + r) * 16 + c16] = v;
  }
}

// ------------- aggregate (R7-verbatim): padded CSR, selfw prefetch, ----------
// branch-free batches, mod-3 deep pipeline. 8 nodes/wave. The selfw prefetch
// + select-chain flush keeps ~52 VGPRs of independent gather state live —
// measured best (68us); do not "simplify" (R10's 40-VGPR variant lost depth).
__global__ __launch_bounds__(256) void k_agg(const uint* __restrict__ ms,
    const int* __restrict__ rp, const int* __restrict__ col,
    const float* __restrict__ dinv, const float* __restrict__ bias,
    uint* __restrict__ a, float* __restrict__ bn_sum, float* __restrict__ bn_sq,
    int N) {
  __shared__ float s_sum[128], s_sq[128];
  for (int i = threadIdx.x; i < 128; i += 256) { s_sum[i] = 0.f; s_sq[i] = 0.f; }
  __syncthreads();
  int lane = threadIdx.x & 63;
  int wi = (blockIdx.x * 256 + threadIdx.x) >> 6;
  float b0 = bias[2 * lane], b1 = bias[2 * lane + 1];
  float lsum0 = 0.f, lsq0 = 0.f, lsum1 = 0.f, lsq1 = 0.f;

  int base = wi * 8;
  if (base < N) {
    int vend = (base + 8 < N) ? base + 8 : N;
    int nv = vend - base;
    int rpi = base + lane; if (rpi > vend) rpi = vend;
    int rp_l = rp[rpi];
    int dvi = base + (lane & 7); if (dvi >= N) dvi = N - 1;
    float dv_l = dinv[dvi];
    // self-loop rows (contiguous) all issued upfront
    int sb1 = base + 1 < N ? base + 1 : N;
    int sb2 = base + 2 < N ? base + 2 : N;
    int sb3 = base + 3 < N ? base + 3 : N;
    int sb4 = base + 4 < N ? base + 4 : N;
    int sb5 = base + 5 < N ? base + 5 : N;
    int sb6 = base + 6 < N ? base + 6 : N;
    int sb7 = base + 7 < N ? base + 7 : N;
    uint sw0 = ms[(size_t)base * 64 + lane];
    uint sw1 = ms[(size_t)sb1 * 64 + lane];
    uint sw2 = ms[(size_t)sb2 * 64 + lane];
    uint sw3 = ms[(size_t)sb3 * 64 + lane];
    uint sw4 = ms[(size_t)sb4 * 64 + lane];
    uint sw5 = ms[(size_t)sb5 * 64 + lane];
    uint sw6 = ms[(size_t)sb6 * 64 + lane];
    uint sw7 = ms[(size_t)sb7 * 64 + lane];

    int e0 = __shfl(rp_l, 0, 64);
    int e1 = __shfl(rp_l, nv, 64);
    int j = 0, v = base;
    int end_cur = __shfl(rp_l, 1, 64);
    float dv = __shfl(dv_l, 0, 64);
    float acc0 = 0.f, acc1 = 0.f;
    int e = e0;
    int nb8 = (e1 - e0) >> 3;        // exact: padded segments are x8

#define FLUSHN() do { \
    uint sw = sw0; \
    sw = (j == 1) ? sw1 : sw; sw = (j == 2) ? sw2 : sw; \
    sw = (j == 3) ? sw3 : sw; sw = (j == 4) ? sw4 : sw; \
    sw = (j == 5) ? sw5 : sw; sw = (j == 6) ? sw6 : sw; \
    sw = (j == 7) ? sw7 : sw; \
    float a0 = fmaxf(dv * (acc0 + BLO(sw)) + b0, 0.f); \
    float a1 = fmaxf(dv * (acc1 + BHI(sw)) + b1, 0.f); \
    uint wpk = pk_bf16(a0, a1); \
    a[(size_t)v * 64 + lane] = wpk; \
    float r0 = BLO(wpk), r1 = BHI(wpk); \
    lsum0 += r0; lsq0 += r0 * r0; lsum1 += r1; lsq1 += r1 * r1; \
    ++v; ++j; \
    if (v < vend) { \
      end_cur = __shfl(rp_l, j + 1, 64); \
      dv = __shfl(dv_l, j, 64); \
      acc0 = 0.f; acc1 = 0.f; \
    } \
  } while (0)

#define COL16(off) col[(off) + (lane & 15)]
#define GATHER(W, CU, HALF) do { \
    _Pragma("unroll") \
    for (int jj = 0; jj < 8; ++jj) { \
      int u = __shfl((int)(CU), (HALF) * 8 + jj, 64); \
      W[jj] = ms[(size_t)u * 64 + lane]; \
    } \
  } while (0)
#define STEP(W) do { \
    _Pragma("unroll") \
    for (int jj = 0; jj < 8; ++jj) { acc0 += BLO(W[jj]); acc1 += BHI(W[jj]); } \
    e += 8; \
    if (e == end_cur) FLUSHN(); \
  } while (0)

    uint cu0 = 0, cu1 = 0, cu2 = 0;
    uint w0[8], w1[8], w2[8];
    cu0 = COL16(e0);                               // batches 0,1
    if (nb8 > 2) cu1 = COL16(e0 + 16);             // batches 2,3
    GATHER(w0, cu0, 0);                            // batch 0
    if (nb8 > 1) GATHER(w1, cu0, 1);               // batch 1

    for (int k = 0; k < nb8; k += 6) {
      if (k + 4 < nb8) cu2 = COL16(e0 + (k + 4) * 8);   // batches k+4,k+5
      if (k + 2 < nb8) GATHER(w2, cu1, 0);              // batch k+2
      STEP(w0);                                          // batch k
      if (k + 3 < nb8) GATHER(w0, cu1, 1);              // batch k+3
      if (k + 1 < nb8) STEP(w1);                        // batch k+1
      if (k + 6 < nb8) cu0 = COL16(e0 + (k + 6) * 8);   // batches k+6,k+7
      if (k + 4 < nb8) GATHER(w1, cu2, 0);              // batch k+4
      if (k + 2 < nb8) STEP(w2);                        // batch k+2
      if (k + 5 < nb8) GATHER(w2, cu2, 1);              // batch k+5
      if (k + 3 < nb8) STEP(w0);                        // batch k+3
      if (k + 8 < nb8) cu1 = COL16(e0 + (k + 8) * 8);   // batches k+8,k+9
      if (k + 6 < nb8) GATHER(w0, cu0, 0);              // batch k+6
      if (k + 4 < nb8) STEP(w1);                        // batch k+4
      if (k + 7 < nb8) GATHER(w1, cu0, 1);              // batch k+7
      if (k + 5 < nb8) STEP(w2);                        // batch k+5
    }
#undef FLUSHN
#undef COL16
#undef GATHER
#undef STEP
  }

  atomicAdd(&s_sum[2 * lane], lsum0);
  atomicAdd(&s_sum[2 * lane + 1], lsum1);
  atomicAdd(&s_sq[2 * lane], lsq0);
  atomicAdd(&s_sq[2 * lane + 1], lsq1);
  __syncthreads();
  for (int i = threadIdx.x; i < 128; i += 256) {
    atomicAdd(&bn_sum[i], s_sum[i]);
    atomicAdd(&bn_sq[i], s_sq[i]);
  }
}

// ------- fused readout: one wave per graph, BN(fold in-lane)+relu+res+mean ---
__global__ __launch_bounds__(256) void k_poolout(const uint* __restrict__ a,
    const uint* __restrict__ hold,
    const float* __restrict__ bn_sum, const float* __restrict__ bn_sq,
    const float* __restrict__ gamma, const float* __restrict__ beta,
    const int* __restrict__ gstart,
    const float* __restrict__ lw, const float* __restrict__ lb,
    float* __restrict__ out, int G, float invN) {
  int g = (blockIdx.x * 256 + threadIdx.x) >> 6;
  int lane = threadIdx.x & 63;
  if (g >= G) return;
  float2 su = *(const float2*)(bn_sum + 2 * lane);
  float2 sq = *(const float2*)(bn_sq + 2 * lane);
  float2 gm = *(const float2*)(gamma + 2 * lane);
  float2 bt = *(const float2*)(beta + 2 * lane);
  float m0 = su.x * invN, m1 = su.y * invN;
  float sc0 = gm.x * rsqrtf(sq.x * invN - m0 * m0 + 1e-5f);
  float sc1 = gm.y * rsqrtf(sq.y * invN - m1 * m1 + 1e-5f);
  float bb0 = bt.x - m0 * sc0, bb1 = bt.y - m1 * sc1;
  int s0 = gstart[g], s1 = gstart[g + 1];
  float acc0 = 0.f, acc1 = 0.f;
  for (int v = s0; v < s1; ++v) {
    uint av = a[(size_t)v * 64 + lane];
    uint hv = hold[(size_t)v * 64 + lane];
    acc0 += fmaxf(sc0 * BLO(av) + bb0, 0.f) + BLO(hv);
    acc1 += fmaxf(sc1 * BHI(av) + bb1, 0.f) + BHI(hv);
  }
  float inv = 1.f / fmaxf((float)(s1 - s0), 1.f);
  float2 w2 = *(const float2*)(lw + 2 * lane);
  float s = acc0 * inv * w2.x + acc1 * inv * w2.y;
#pragma unroll
  for (int off = 32; off > 0; off >>= 1) s += __shfl_down(s, off, 64);
  if (lane == 0) out[g] = 1.f / (1.f + expf(-(s + lb[0])));
}

extern "C" void kernel_launch(void* const* d_in, const int* in_sizes, int n_in,
                              void* d_out, int out_size, void* d_ws, size_t ws_size,
                              hipStream_t stream) {
  const int* x      = (const int*)d_in[0];
  const int* ei     = (const int*)d_in[1];
  const int* batch  = (const int*)d_in[2];
  const float* emb  = (const float*)d_in[3];
  const float* convW = (const float*)d_in[4];
  const float* convB = (const float*)d_in[5];
  const float* gamma = (const float*)d_in[6];
  const float* beta  = (const float*)d_in[7];
  const float* lw    = (const float*)d_in[8];
  const float* lb    = (const float*)d_in[9];
  float* out = (float*)d_out;

  const int N = in_sizes[2];
  const int E = in_sizes[1] / 2;
  const int G = out_size;
  const int MAXV = in_sizes[3] / (FEAT * H);
  const int L = in_sizes[4] / (H * H);
  const int Npad = (N + 128) & ~127;     // guarantees zero row N exists

  const int* srcp = ei;
  const int* dstp = ei + E;

  char* p = (char*)d_ws;
  auto alloc = [&](size_t bytes) { char* r = p; p += (bytes + 255) & ~255ull; return r; };
  uint*  h    = (uint*)alloc((size_t)Npad * 64 * 4);   // bf16x2 packed residual
  uint*  ms   = (uint*)alloc((size_t)Npad * 64 * 4);   // bf16x2 packed, pre-scaled
  uint*  a    = (uint*)alloc((size_t)Npad * 64 * 4);   // bf16x2 packed activations
  float* dinv = (float*)alloc((size_t)N * 4);
  int* row_ptr = (int*)alloc((size_t)(N + 1) * 4);
  int* col     = (int*)alloc(((size_t)E + 8 * (size_t)N + 64) * 4);  // padded CSR
  int* pcnt    = (int*)alloc((size_t)N * 4);
  int* incl    = (int*)alloc((size_t)N * 4);
  int* bsum    = (int*)alloc(256 * 4);
  uint* wt     = (uint*)alloc((size_t)L * H * 64 * 4); // WT bf16 [l][n][k/2]
  int* gstart  = (int*)alloc((size_t)(G + 1) * 4);
  char* z0 = p;
  int* counts   = (int*)alloc((size_t)N * 4);
  int* cursor   = (int*)alloc((size_t)N * 4);
  float* bn_sum = (float*)alloc((size_t)L * H * 4);
  float* bn_sq  = (float*)alloc((size_t)L * H * 4);
  size_t zbytes = (size_t)(p - z0);

  hipMemsetAsync(z0, 0, zbytes, stream);
  hipMemsetAsync(a + (size_t)N * 64, 0, (size_t)(Npad - N) * 256, stream);

  const int nb = (N + 255) / 256;
  const float invN = 1.0f / (float)N;

  // graph prep
  k_atom<<<Npad / 4, 256, 0, stream>>>(x, emb, h, N, Npad, MAXV);
  k_count<<<(E + 255) / 256, 256, 0, stream>>>(dstp, counts, E);
  k_dinv<<<(N + 255) / 256, 256, 0, stream>>>(counts, dinv, pcnt, N);
  k_scan1<<<nb, 256, 0, stream>>>(pcnt, incl, bsum, N);
  k_scan2<<<1, 256, 0, stream>>>(bsum, nb);
  k_scan3<<<nb, 256, 0, stream>>>(incl, bsum, counts, row_ptr, col, N, N);
  k_fill<<<(E + 255) / 256, 256, 0, stream>>>(srcp, dstp, row_ptr, cursor, col, E);
  k_bound<<<(N + 256) / 256, 256, 0, stream>>>(batch, gstart, N, G);
  k_wt<<<(L * H * 64 + 255) / 256, 256, 0, stream>>>(convW, wt, L * H * 64);

  const int aggWaves = (N + 7) / 8;
  const int aggBlocks = (aggWaves + 3) / 4;

  // layers
  for (int l = 0; l < L; ++l) {
    if (l == 0) {
      k_gemm_mfma<0><<<Npad / 128, 256, 0, stream>>>(
          h, nullptr, nullptr, nullptr, nullptr, nullptr, nullptr, 0.f,
          wt, ms, dinv, N);
    } else {
      k_gemm_mfma<1><<<Npad / 128, 256, 0, stream>>>(
          a, h, h,
          bn_sum + (size_t)(l - 1) * H, bn_sq + (size_t)(l - 1) * H,
          gamma + (size_t)(l - 1) * H, beta + (size_t)(l - 1) * H, invN,
          wt + (size_t)l * H * 64, ms, dinv, N);
    }
    k_agg<<<aggBlocks, 256, 0, stream>>>(ms, row_ptr, col, dinv, convB + (size_t)l * H,
                                         a, bn_sum + (size_t)l * H, bn_sq + (size_t)l * H, N);
  }

  // fused readout (final BN fold + relu + residual + mean-pool + linear + sigmoid)
  k_poolout<<<(G + 3) / 4, 256, 0, stream>>>(
      a, h, bn_sum + (size_t)(L - 1) * H, bn_sq + (size_t)(L - 1) * H,
      gamma + (size_t)(L - 1) * H, beta + (size_t)(L - 1) * H,
      gstart, lw, lb, out, G, invN);
}